// Round 15
// baseline (37.622 us; speedup 1.0000x reference)
//
#include <hip/hip_runtime.h>

#define N 512
#define D 128
// 1000 * log2(e): sigmoid(x/K) = 1/(1+exp(-x*1000)) = 1/(1+exp2(-x*SCALE))
#define RS_SCALE 1442.6950408889634f
// bucket width == far-threshold 18 (sigmoid saturated to 0/1 within 2^-18)
#define W_INV (1.0f / 18.0f)
#define B_OFF 1530.0f
#define PADV -1600.0f   // pad sorts below all real rs (>= -1442.7), bucket 0
#define NB 172
// PROBE: front (hist+scan+scatter) dilation factor; reps produce identical
// LDS state -> result bit-identical, duration = base + (FREP-1)*front
#define FREP 12

static __device__ __forceinline__ float rcp_fast(float x) {
    return __builtin_amdgcn_rcpf(x);
}
static __device__ __forceinline__ float exp2_fast(float x) {
    return __builtin_amdgcn_exp2f(x);
}

// ---------------- K1: raw-dot GEMM x.x^T (16x32 tiles, 512 blocks) ----------
// IDENTICAL to R14 (needed for probe algebra).
__global__ __launch_bounds__(256) void map_sim_kernel(
    const float* __restrict__ x, float* __restrict__ rs,
    int* __restrict__ ticket)
{
    const int bi = blockIdx.x;   // 32 row-panels of 16
    const int bj = blockIdx.y;   // 16 col-panels of 32
    const int t = threadIdx.x;
    __shared__ float As[16 * D];
    __shared__ float Bs[32 * D];

    if (bi == 0 && bj == 0 && t == 0) *ticket = 0;  // reset fence counter

#pragma unroll
    for (int s = 0; s < 2; ++s) {
        int ch = t + 256 * s;
        int row = ch >> 5, c4 = ch & 31;
        *(float4*)(As + row * D + ((c4 ^ row) << 2)) =
            *(const float4*)(x + (bi * 16 + row) * D + c4 * 4);
    }
#pragma unroll
    for (int s = 0; s < 4; ++s) {
        int ch = t + 256 * s;
        int row = ch >> 5, c4 = ch & 31;
        *(float4*)(Bs + row * D + ((c4 ^ row) << 2)) =
            *(const float4*)(x + (bj * 32 + row) * D + c4 * 4);
    }
    __syncthreads();

    const int c = t & 31;
    const int rp = t >> 5;
    const int ra0 = 2 * rp, ra1 = 2 * rp + 1;
    float acc0 = 0.f, acc1 = 0.f;
#pragma unroll 8
    for (int k4 = 0; k4 < D / 4; ++k4) {
        float4 b = *(const float4*)(Bs + c * D + ((k4 ^ c) << 2));
        float4 a0 = *(const float4*)(As + ra0 * D + ((k4 ^ ra0) << 2));
        float4 a1 = *(const float4*)(As + ra1 * D + ((k4 ^ ra1) << 2));
        acc0 = fmaf(a0.x, b.x, acc0); acc0 = fmaf(a0.y, b.y, acc0);
        acc0 = fmaf(a0.z, b.z, acc0); acc0 = fmaf(a0.w, b.w, acc0);
        acc1 = fmaf(a1.x, b.x, acc1); acc1 = fmaf(a1.y, b.y, acc1);
        acc1 = fmaf(a1.z, b.z, acc1); acc1 = fmaf(a1.w, b.w, acc1);
    }
    const int gc = bj * 32 + c;
    rs[(bi * 16 + ra0) * N + gc] = acc0;
    rs[(bi * 16 + ra1) * N + gc] = acc1;
}

// ---------------- K2: counting-sort (front dilated x12) + windowed AP -------
__global__ __launch_bounds__(512) void map_ap_kernel(
    const float* __restrict__ rs, const int* __restrict__ tgt,
    float2* __restrict__ av, int* __restrict__ ticket,
    float* __restrict__ out)
{
    const int i = blockIdx.x, t = threadIdx.x;
    const int lane = t & 63;
    __shared__ int hist[256];   // packed (count<<10)|gtcount -> inclusive scan
    __shared__ int offs[NB];
    __shared__ int wtot[4];
    __shared__ unsigned gbits[16];            // gt bitmask by sorted position
    __shared__ __align__(16) float skey[N];   // bucket-sorted keys
    __shared__ float red[16];
    __shared__ int amLast;

    // issue global loads first (latency overlaps LDS init)
    const int ti = tgt[i];
    const float draw = rs[i * N + t];
    const float ssT = rs[t * N + t];     // diag = ||x_t||^2 (L2-hot)
    const float ssI = rs[i * N + i];
    const int tgT = tgt[t];

    const bool self = (t == i);
    const float invT = rcp_fast(fmaxf(sqrtf(ssT), 1e-8f));
    const float invI = rcp_fast(fmaxf(sqrtf(ssI), 1e-8f));
    const float val = self ? PADV : draw * invT * invI * RS_SCALE;
    const int gti = (!self && tgT == ti) ? 1 : 0;
    int q = (int)((val + B_OFF) * W_INV);
    q = max(0, min(NB - 1, q));

    // ---- PROBE: the entire sort-front repeats FREP times; every rep
    // rebuilds identical LDS state (atomics are side-effectful, never
    // elided; each rep re-zeroes its tables) ----
#pragma unroll 1
    for (int rep = 0; rep < FREP; ++rep) {
        __syncthreads();   // prev rep's LDS fully consumed
        if (t < 256) hist[t] = 0;
        if (t < NB) offs[t] = 0;
        if (t < 16) gbits[t] = 0u;
        __syncthreads();
        atomicAdd(&hist[q], (1 << 10) | gti);
        __syncthreads();

        // wave-level inclusive scan of hist[0..255] (waves 0-3)
        int v = (t < 256) ? hist[t] : 0;
#pragma unroll
        for (int off = 1; off < 64; off <<= 1) {
            int u = __shfl_up(v, off);
            if (lane >= off) v += u;
        }
        if (t < 256 && lane == 63) wtot[t >> 6] = v;
        __syncthreads();
        if (t < 256) {
            int w = t >> 6, add = 0;
            if (w > 0) add += wtot[0];
            if (w > 1) add += wtot[1];
            if (w > 2) add += wtot[2];
            hist[t] = v + add;
        }
        __syncthreads();

        // scatter: key to skey[], gt flag to bitmask
        {
            int base = (q > 0) ? (hist[q - 1] >> 10) : 0;
            int pos = base + atomicAdd(&offs[q], 1);
            skey[pos] = val;
            if (gti) atomicOr(&gbits[pos >> 5], 1u << (pos & 31));
        }
        __syncthreads();
    }

    // windowed sigmoid AP, position p = t; 16-lane-group bounds
    const int totGt = hist[NB - 1] & 1023;
    const float4* sk4 = (const float4*)skey;

    const float rj = skey[t];
    const float gtj = (float)((gbits[t >> 5] >> (t & 31)) & 1u);
    int qj = (int)((rj + B_OFF) * W_INV);
    qj = max(0, min(NB - 1, qj));
    const int gl = lane & 48;            // first lane of 16-lane group
    const int qlo = __shfl(qj, gl);
    const int qhi = __shfl(qj, gl + 15);
    const int lo = (qlo > 1) ? (hist[qlo - 2] >> 10) : 0;
    const int e1 = min(qhi + 1, NB - 1);
    const int hi = hist[e1] >> 10;

    float dsum = (float)(N - hi);   // buckets >= qhi+2: exactly 1 each
    float gsum = (float)(totGt - (hist[e1] & 1023));

    float d0 = 0.f, d1 = 0.f, d2 = 0.f, d3 = 0.f;
    float g0 = 0.f, g1 = 0.f, g2 = 0.f, g3 = 0.f;
    int k = lo & ~7;                // elems in [k, lo) saturate to 0: exact
    for (; k + 8 <= hi; k += 8) {
        float4 ka = sk4[k >> 2];        // group-uniform address
        float4 kb = sk4[(k >> 2) + 1];
        unsigned gw = (gbits[k >> 5] >> (k & 31)) & 0xffu;
        float s0 = rcp_fast(1.f + exp2_fast(rj - ka.x));
        float s1 = rcp_fast(1.f + exp2_fast(rj - ka.y));
        float s2 = rcp_fast(1.f + exp2_fast(rj - ka.z));
        float s3 = rcp_fast(1.f + exp2_fast(rj - ka.w));
        float s4 = rcp_fast(1.f + exp2_fast(rj - kb.x));
        float s5 = rcp_fast(1.f + exp2_fast(rj - kb.y));
        float s6 = rcp_fast(1.f + exp2_fast(rj - kb.z));
        float s7 = rcp_fast(1.f + exp2_fast(rj - kb.w));
        d0 += s0 + s4; d1 += s1 + s5; d2 += s2 + s6; d3 += s3 + s7;
        g0 += ((gw      ) & 1u) ? s0 : 0.f;
        g1 += ((gw >> 1u) & 1u) ? s1 : 0.f;
        g2 += ((gw >> 2u) & 1u) ? s2 : 0.f;
        g3 += ((gw >> 3u) & 1u) ? s3 : 0.f;
        g0 += ((gw >> 4u) & 1u) ? s4 : 0.f;
        g1 += ((gw >> 5u) & 1u) ? s5 : 0.f;
        g2 += ((gw >> 6u) & 1u) ? s6 : 0.f;
        g3 += ((gw >> 7u) & 1u) ? s7 : 0.f;
    }
    dsum += (d0 + d1) + (d2 + d3);
    gsum += (g0 + g1) + (g2 + g3);
    for (; k < hi; ++k) {           // scalar tail (<8 iters)
        float s = rcp_fast(1.f + exp2_fast(rj - skey[k]));
        dsum += s;
        gsum += ((gbits[k >> 5] >> (k & 31)) & 1u) ? s : 0.f;
    }

    float apAcc = gtj * gsum * rcp_fast(dsum + 0.5f);  // pad thread: gtj = 0
    float npAcc = gtj;

    // block reduction (8 waves)
#pragma unroll
    for (int off = 32; off; off >>= 1) {
        apAcc += __shfl_down(apAcc, off);
        npAcc += __shfl_down(npAcc, off);
    }
    if (lane == 0) { red[(t >> 6) * 2] = apAcc; red[(t >> 6) * 2 + 1] = npAcc; }
    __syncthreads();
    if (t == 0) {
        float A = 0.f, P = 0.f;
#pragma unroll
        for (int kk = 0; kk < 8; ++kk) { A += red[2 * kk]; P += red[2 * kk + 1]; }
        av[i] = make_float2((P > 0.f) ? (A * rcp_fast(P)) : 0.f,
                            (P > 0.f) ? 1.f : 0.f);
        __threadfence();                       // release av[i]
        int old = atomicAdd(ticket, 1);
        amLast = (old == (int)gridDim.x - 1) ? 1 : 0;
    }
    __syncthreads();

    if (amLast) {  // last block (uniform) reduces av[] and writes out
        __threadfence();                       // acquire
        float2 p = av[t];
        float a = p.x, vv = p.y;
#pragma unroll
        for (int off = 32; off; off >>= 1) {
            a += __shfl_down(a, off);
            vv += __shfl_down(vv, off);
        }
        if (lane == 0) { red[(t >> 6) * 2] = a; red[(t >> 6) * 2 + 1] = vv; }
        __syncthreads();
        if (t == 0) {
            float A = 0.f, V = 0.f;
#pragma unroll
            for (int kk = 0; kk < 8; ++kk) { A += red[2 * kk]; V += red[2 * kk + 1]; }
            out[0] = 1.0f - A * rcp_fast(V);
        }
    }
}

extern "C" void kernel_launch(void* const* d_in, const int* in_sizes, int n_in,
                              void* d_out, int out_size, void* d_ws, size_t ws_size,
                              hipStream_t stream) {
    const float* x = (const float*)d_in[0];
    const int* tgt = (const int*)d_in[1];
    float* out = (float*)d_out;

    float* rs = (float*)d_ws;                                 // 1 MB
    float2* av = (float2*)((char*)d_ws + N * N * 4);          // 4 KB
    int* ticket = (int*)((char*)d_ws + N * N * 4 + N * 8);    // 4 B

    map_sim_kernel<<<dim3(32, 16), 256, 0, stream>>>(x, rs, ticket);
    map_ap_kernel<<<N, 512, 0, stream>>>(rs, tgt, av, ticket, out);
}

// Round 16
// 27.991 us; speedup vs baseline: 1.3441x; 1.3441x over previous
//
#include <hip/hip_runtime.h>

#define N 512
#define D 128
// 1000 * log2(e): sigmoid(x/K) = 1/(1+exp(-x*1000)) = 1/(1+exp2(-x*SCALE))
#define RS_SCALE 1442.6950408889634f
// bucket width == far-threshold 11: bucket distance >=2 guarantees diff > 11
// -> far sigmoid error <= 2^-11 per elem (~2e-3 summed; threshold is 1.9e-2)
#define W_INV (1.0f / 11.0f)
#define B_OFF 1444.0f
#define PADV -1600.0f   // pad clamps to bucket 0; as an l-elem saturates to 0
#define NB 256
#define MAXGT 64        // >= max positives per row (32 classes over 512 rows)

static __device__ __forceinline__ float rcp_fast(float x) {
    return __builtin_amdgcn_rcpf(x);
}
static __device__ __forceinline__ float exp2_fast(float x) {
    return __builtin_amdgcn_exp2f(x);
}

// ---------------- K1: raw-dot GEMM x.x^T (16x32 tiles, 512 blocks) ----------
// IDENTICAL to R14 (probe algebra). diag rs[c][c] = ||x_c||^2.
__global__ __launch_bounds__(256) void map_sim_kernel(
    const float* __restrict__ x, float* __restrict__ rs,
    int* __restrict__ ticket)
{
    const int bi = blockIdx.x;   // 32 row-panels of 16
    const int bj = blockIdx.y;   // 16 col-panels of 32
    const int t = threadIdx.x;
    __shared__ float As[16 * D];
    __shared__ float Bs[32 * D];

    if (bi == 0 && bj == 0 && t == 0) *ticket = 0;  // reset fence counter

#pragma unroll
    for (int s = 0; s < 2; ++s) {
        int ch = t + 256 * s;
        int row = ch >> 5, c4 = ch & 31;
        *(float4*)(As + row * D + ((c4 ^ row) << 2)) =
            *(const float4*)(x + (bi * 16 + row) * D + c4 * 4);
    }
#pragma unroll
    for (int s = 0; s < 4; ++s) {
        int ch = t + 256 * s;
        int row = ch >> 5, c4 = ch & 31;
        *(float4*)(Bs + row * D + ((c4 ^ row) << 2)) =
            *(const float4*)(x + (bj * 32 + row) * D + c4 * 4);
    }
    __syncthreads();

    const int c = t & 31;
    const int rp = t >> 5;
    const int ra0 = 2 * rp, ra1 = 2 * rp + 1;
    float acc0 = 0.f, acc1 = 0.f;
#pragma unroll 8
    for (int k4 = 0; k4 < D / 4; ++k4) {
        float4 b = *(const float4*)(Bs + c * D + ((k4 ^ c) << 2));
        float4 a0 = *(const float4*)(As + ra0 * D + ((k4 ^ ra0) << 2));
        float4 a1 = *(const float4*)(As + ra1 * D + ((k4 ^ ra1) << 2));
        acc0 = fmaf(a0.x, b.x, acc0); acc0 = fmaf(a0.y, b.y, acc0);
        acc0 = fmaf(a0.z, b.z, acc0); acc0 = fmaf(a0.w, b.w, acc0);
        acc1 = fmaf(a1.x, b.x, acc1); acc1 = fmaf(a1.y, b.y, acc1);
        acc1 = fmaf(a1.z, b.z, acc1); acc1 = fmaf(a1.w, b.w, acc1);
    }
    const int gc = bj * 32 + c;
    rs[(bi * 16 + ra0) * N + gc] = acc0;
    rs[(bi * 16 + ra1) * N + gc] = acc1;
}

// ---------------- K2: counting-sort + windowed AP (gt split out) ------------
__global__ __launch_bounds__(512) void map_ap_kernel(
    const float* __restrict__ rs, const int* __restrict__ tgt,
    float2* __restrict__ av, int* __restrict__ ticket,
    float* __restrict__ out)
{
    const int i = blockIdx.x, t = threadIdx.x;
    const int lane = t & 63;
    __shared__ int hist[NB];    // packed (count<<10)|gtcount -> inclusive scan
    __shared__ int offs[NB];
    __shared__ int wtot[4];
    __shared__ unsigned gbits[16];            // gt bitmask by sorted position
    __shared__ __align__(16) float skey[N];   // bucket-sorted keys
    __shared__ float gkey[MAXGT];             // gt keys, sorted-position order
    __shared__ float red[16];
    __shared__ int amLast;

    // issue global loads first (latency overlaps LDS init)
    const int ti = tgt[i];
    const float draw = rs[i * N + t];
    const float ssT = rs[t * N + t];     // diag = ||x_t||^2 (L2-hot)
    const float ssI = rs[i * N + i];
    const int tgT = tgt[t];

    if (t < NB) { hist[t] = 0; offs[t] = 0; }
    if (t < 16) gbits[t] = 0u;

    const bool self = (t == i);
    const float invT = rcp_fast(fmaxf(sqrtf(ssT), 1e-8f));
    const float invI = rcp_fast(fmaxf(sqrtf(ssI), 1e-8f));
    const float val = self ? PADV : draw * invT * invI * RS_SCALE;
    const int gti = (!self && tgT == ti) ? 1 : 0;
    int q = (int)((val + B_OFF) * W_INV);
    q = max(0, min(NB - 1, q));
    __syncthreads();
    atomicAdd(&hist[q], (1 << 10) | gti);
    __syncthreads();

    // wave-level inclusive scan of hist[0..255] (waves 0-3, packed fields)
    int v = (t < NB) ? hist[t] : 0;
#pragma unroll
    for (int off = 1; off < 64; off <<= 1) {
        int u = __shfl_up(v, off);
        if (lane >= off) v += u;
    }
    if (t < NB && lane == 63) wtot[t >> 6] = v;
    __syncthreads();
    if (t < NB) {
        int w = t >> 6, add = 0;
        if (w > 0) add += wtot[0];
        if (w > 1) add += wtot[1];
        if (w > 2) add += wtot[2];
        hist[t] = v + add;
    }
    __syncthreads();

    // scatter: key to skey[], gt flag to position bitmask
    {
        int base = (q > 0) ? (hist[q - 1] >> 10) : 0;
        int pos = base + atomicAdd(&offs[q], 1);
        skey[pos] = val;
        if (gti) atomicOr(&gbits[pos >> 5], 1u << (pos & 31));
    }
    __syncthreads();

    // deterministic compact gt-key array (rank = popcount prefix of gbits)
    const unsigned myw = gbits[t >> 5];
    const int mybit = (myw >> (t & 31)) & 1;
    if (mybit) {
        int r = __popc(myw & ((1u << (t & 31)) - 1u));
#pragma unroll
        for (int u = 0; u < 16; ++u)
            if (u < (t >> 5)) r += __popc(gbits[u]);
        gkey[r] = skey[t];
    }
    __syncthreads();

    const int totGt = hist[NB - 1] & 1023;   // = ngt
    const float4* sk4 = (const float4*)skey;

    // windowed dsum, position p = t; 16-lane-group bounds
    const float rj = skey[t];
    const float gtj = (float)mybit;
    int qj = (int)((rj + B_OFF) * W_INV);
    qj = max(0, min(NB - 1, qj));
    const int gl = lane & 48;            // first lane of 16-lane group
    const int qlo = __shfl(qj, gl);
    const int qhi = __shfl(qj, gl + 15);
    const int lo = (qlo > 1) ? (hist[qlo - 2] >> 10) : 0;
    const int e1 = min(qhi + 1, NB - 1);
    const int hi = hist[e1] >> 10;

    float dsum = (float)(N - hi);   // buckets >= qhi+2: ~1 each (err<=2^-11)

    float d0 = 0.f, d1 = 0.f, d2 = 0.f, d3 = 0.f;
    int k = lo & ~7;                // extra elems below lo: computed exactly
    for (; k + 8 <= hi; k += 8) {
        float4 ka = sk4[k >> 2];        // group-uniform address (broadcast)
        float4 kb = sk4[(k >> 2) + 1];
        d0 += rcp_fast(1.f + exp2_fast(rj - ka.x));
        d1 += rcp_fast(1.f + exp2_fast(rj - ka.y));
        d2 += rcp_fast(1.f + exp2_fast(rj - ka.z));
        d3 += rcp_fast(1.f + exp2_fast(rj - ka.w));
        d0 += rcp_fast(1.f + exp2_fast(rj - kb.x));
        d1 += rcp_fast(1.f + exp2_fast(rj - kb.y));
        d2 += rcp_fast(1.f + exp2_fast(rj - kb.z));
        d3 += rcp_fast(1.f + exp2_fast(rj - kb.w));
    }
    dsum += (d0 + d1) + (d2 + d3);
    for (; k < hi; ++k)             // scalar tail (<8 iters)
        dsum += rcp_fast(1.f + exp2_fast(rj - skey[k]));

    // gsum: all gt elements, saturating sigmoid (exact 0/1 at extremes;
    // includes self-position at 0.5 when this position is gt)
    float gsum = 0.f;
    for (int r = 0; r < totGt; ++r)
        gsum += rcp_fast(1.f + exp2_fast(rj - gkey[r]));

    float apAcc = gtj * gsum * rcp_fast(dsum + 0.5f);  // pad thread: gtj = 0
    float npAcc = gtj;

    // block reduction (8 waves)
#pragma unroll
    for (int off = 32; off; off >>= 1) {
        apAcc += __shfl_down(apAcc, off);
        npAcc += __shfl_down(npAcc, off);
    }
    if (lane == 0) { red[(t >> 6) * 2] = apAcc; red[(t >> 6) * 2 + 1] = npAcc; }
    __syncthreads();
    if (t == 0) {
        float A = 0.f, P = 0.f;
#pragma unroll
        for (int kk = 0; kk < 8; ++kk) { A += red[2 * kk]; P += red[2 * kk + 1]; }
        av[i] = make_float2((P > 0.f) ? (A * rcp_fast(P)) : 0.f,
                            (P > 0.f) ? 1.f : 0.f);
        __threadfence();                       // release av[i]
        int old = atomicAdd(ticket, 1);
        amLast = (old == (int)gridDim.x - 1) ? 1 : 0;
    }
    __syncthreads();

    if (amLast) {  // last block (uniform) reduces av[] and writes out
        __threadfence();                       // acquire
        float2 p = av[t];
        float a = p.x, vv = p.y;
#pragma unroll
        for (int off = 32; off; off >>= 1) {
            a += __shfl_down(a, off);
            vv += __shfl_down(vv, off);
        }
        if (lane == 0) { red[(t >> 6) * 2] = a; red[(t >> 6) * 2 + 1] = vv; }
        __syncthreads();
        if (t == 0) {
            float A = 0.f, V = 0.f;
#pragma unroll
            for (int kk = 0; kk < 8; ++kk) { A += red[2 * kk]; V += red[2 * kk + 1]; }
            out[0] = 1.0f - A * rcp_fast(V);
        }
    }
}

extern "C" void kernel_launch(void* const* d_in, const int* in_sizes, int n_in,
                              void* d_out, int out_size, void* d_ws, size_t ws_size,
                              hipStream_t stream) {
    const float* x = (const float*)d_in[0];
    const int* tgt = (const int*)d_in[1];
    float* out = (float*)d_out;

    float* rs = (float*)d_ws;                                 // 1 MB
    float2* av = (float2*)((char*)d_ws + N * N * 4);          // 4 KB
    int* ticket = (int*)((char*)d_ws + N * N * 4 + N * 8);    // 4 B

    map_sim_kernel<<<dim3(32, 16), 256, 0, stream>>>(x, rs, ticket);
    map_ap_kernel<<<N, 512, 0, stream>>>(rs, tgt, av, ticket, out);
}